// Round 14
// baseline (270.741 us; speedup 1.0000x reference)
//
#include <hip/hip_runtime.h>

// Problem constants: B=4, C=64, Z=H=W=64, modes 16, rank 16.
#define TWOPI 6.28318530717958647692f

typedef float fvec4 __attribute__((ext_vector_type(4)));

// cos/sin(2*pi*k/64) as constexpr (compile-time literals after full unroll)
constexpr float COSQ[17] = {
  1.0f, 0.995184727f, 0.980785280f, 0.956940336f, 0.923879533f,
  0.881921264f, 0.831469612f, 0.773010453f, 0.707106781f,
  0.634393284f, 0.555570233f, 0.471396737f, 0.382683432f,
  0.290284677f, 0.195090322f, 0.098017140f, 0.0f
};
__host__ __device__ constexpr float cos64f(int k) {
  k &= 63;
  return (k <= 16) ? COSQ[k] : (k < 32) ? -COSQ[32 - k]
       : (k <= 48) ? -COSQ[k - 32] : COSQ[64 - k];
}
__host__ __device__ constexpr float sin64f(int k) { return cos64f(k + 48); }

// t-layout of the 256 (hf,wf) pairs:  t = j*64 + wq*16 + hf, wf = wq+4j.
// decode: hf = t&15, wf = ((t>>4)&3) + 4*(t>>6); encode: t(hf,wf) =
// (wf>>2)*64 + (wf&3)*16 + hf.

// ---------------- fused: core partial sums + forward H+W DFT ---------------
// blocks 0..255: core-tensor partial reduction (nontemporal streamed read so
// x keeps its L3 residency). blocks 256..4351: one (b,c,z) plane per wave.
// Stage 1 uses radix-4 DIT: h = 4q+s -> four real DFT-16s (conjugate
// symmetric) + 3-term twiddle combine: ~730 FMA/lane vs 1984 direct.
// launch_bounds(256,5): VGPR cap ~102 (LDS already caps at 5 blocks/CU).
__global__ __launch_bounds__(256, 5) void k_fwd_wh_core(
    const float* __restrict__ x, float2* __restrict__ A2,
    const float* __restrict__ a0, const float* __restrict__ a1,
    const float* __restrict__ a2, const float* __restrict__ a3,
    float* __restrict__ partial) {
  __shared__ float2 T[4][64][16];   // [w][hf ^ (w&15)] swizzled, 32 KB
  if (blockIdx.x < 256) {
    float* red = (float*)T;         // alias: core branch never touches T
    int bx = blockIdx.x & 63, by = blockIdx.x >> 6;
    const float* p = by == 0 ? a0 : by == 1 ? a1 : by == 2 ? a2 : a3;
    const fvec4* p4 = (const fvec4*)p;
    float s = 0.f;
    int base = bx * 4096 + threadIdx.x;
    #pragma unroll
    for (int i = 0; i < 16; ++i) {
      fvec4 v = __builtin_nontemporal_load(&p4[base + i * 256]);
      s += (v.x + v.y) + (v.z + v.w);
    }
    red[threadIdx.x] = s;
    __syncthreads();
    for (int off = 128; off; off >>= 1) {
      if (threadIdx.x < off) red[threadIdx.x] += red[threadIdx.x + off];
      __syncthreads();
    }
    if (threadIdx.x == 0) partial[by * 64 + bx] = red[0];
    return;
  }
  int wave = threadIdx.x >> 6, lane = threadIdx.x & 63;
  int plane = (blockIdx.x - 256) * 4 + wave;     // (b*64+c)*64+z
  const float* xp = x + (size_t)plane * 4096 + lane;   // lane = w
  // stage 1 (radix-4 DIT): X[hf] = sum_s W64^{s hf} Y_s[hf],
  // Y_s[k] = DFT16 of x[4q+s] (real -> Y_s[16-k] = conj Y_s[k]).
  float cre[16], cim[16];
  #pragma unroll
  for (int s = 0; s < 4; ++s) {
    float x0 = xp[s * 64], x32 = xp[(32 + s) * 64];
    float u[8], d[8];                 // q = 1..7
    #pragma unroll
    for (int q = 1; q < 8; ++q) {
      float va = xp[(4 * q + s) * 64];
      float vb = xp[(64 - 4 * q + s) * 64];
      u[q] = va + vb;
      d[q] = va - vb;
    }
    float yr[9], yi[9];
    #pragma unroll
    for (int k = 0; k <= 8; ++k) {
      float r = x0 + ((k & 1) ? -x32 : x32);
      float i2 = 0.f;
      #pragma unroll
      for (int q = 1; q < 8; ++q) {
        r = fmaf(u[q], cos64f(4 * q * k), r);
        i2 = fmaf(d[q], -sin64f(4 * q * k), i2);
      }
      yr[k] = r; yi[k] = i2;
    }
    #pragma unroll
    for (int hf = 0; hf < 16; ++hf) {
      const int k = (hf <= 8) ? hf : 16 - hf;
      float Yr = yr[k];
      float Yi = (hf <= 8) ? yi[k] : -yi[k];
      if (s == 0) {
        cre[hf] = Yr;
        cim[hf] = Yi;
      } else {
        const float c = cos64f(s * hf), sn = sin64f(s * hf);
        cre[hf] = fmaf(Yr, c, fmaf(Yi, sn, cre[hf]));
        cim[hf] = fmaf(Yi, c, fmaf(-Yr, sn, cim[hf]));
      }
    }
  }
  {
    int sw = lane & 15;
    #pragma unroll
    for (int hf = 0; hf < 16; ++hf)
      T[wave][lane][hf ^ sw] = make_float2(cre[hf], cim[hf]);
  }
  // same-wave producer/consumer on T: no barrier needed.
  // stage 2 (paired): A[hf][wf] = sum_w T[w][hf] e^{-2pi i w wf/64}
  int hf = lane & 15, wq = lane >> 4;
  float2 rot[4], CS[4], acc[4];
  float2 T0 = T[wave][0][hf], T32 = T[wave][32][hf];   // (0&15)=(32&15)=0
  #pragma unroll
  for (int j = 0; j < 4; ++j) {
    // wf = wq + 4j; wq in 0..3 -> 3-way literal select, no sincosf
    float c = (wq == 0) ? cos64f(4 * j)
            : (wq == 1) ? cos64f(4 * j + 1)
            : (wq == 2) ? cos64f(4 * j + 2) : cos64f(4 * j + 3);
    float s = (wq == 0) ? sin64f(4 * j)
            : (wq == 1) ? sin64f(4 * j + 1)
            : (wq == 2) ? sin64f(4 * j + 2) : sin64f(4 * j + 3);
    rot[j] = make_float2(c, s);
    CS[j] = make_float2(c, s);        // value at w=1
    float sgn = ((wq + 4 * j) & 1) ? -1.f : 1.f;
    acc[j] = make_float2(T0.x + sgn * T32.x, T0.y + sgn * T32.y);
  }
  #pragma unroll
  for (int w = 1; w < 32; ++w) {
    float2 a = T[wave][w][hf ^ (w & 15)];
    float2 b2 = T[wave][64 - w][hf ^ ((64 - w) & 15)];
    float Sr = a.x + b2.x, Si = a.y + b2.y;
    float Dr = a.x - b2.x, Di = a.y - b2.y;
    #pragma unroll
    for (int j = 0; j < 4; ++j) {
      float C = CS[j].x, Sn = CS[j].y;
      acc[j].x = fmaf(Sr, C, fmaf(Di, Sn, acc[j].x));
      acc[j].y = fmaf(Si, C, fmaf(-Dr, Sn, acc[j].y));
      float nC = C * rot[j].x - Sn * rot[j].y;
      CS[j].y = fmaf(C, rot[j].y, Sn * rot[j].x);
      CS[j].x = nC;
    }
  }
  float2* dst = A2 + (size_t)plane * 256 + lane;   // t = j*64+lane
  #pragma unroll
  for (int j = 0; j < 4; ++j) dst[j * 64] = acc[j];
}

// ---------------- projection c -> r (+ fused core-final sum) ---------------
// grid (256 bz, 2 rg): each block computes 8 of the 16 ranks.
__global__ __launch_bounds__(256) void k_proj(const float2* __restrict__ A2,
                                              float2* __restrict__ P,
                                              const float* __restrict__ U_in,
                                              const float* __restrict__ partial,
                                              float* __restrict__ S) {
  if (blockIdx.x == 0 && blockIdx.y == 0 && threadIdx.x < 4) {
    float s = 0.f;
    for (int j = 0; j < 64; ++j) s += partial[threadIdx.x * 64 + j];
    S[threadIdx.x] = s;
  }
  __shared__ float sU[1024];
  int t = threadIdx.x;
  #pragma unroll
  for (int i = 0; i < 4; ++i) sU[t + 256 * i] = U_in[t + 256 * i];
  __syncthreads();
  int b = blockIdx.x >> 6, z = blockIdx.x & 63, r0 = blockIdx.y * 8;
  const float2* src = A2 + (((size_t)b * 64) * 64 + z) * 256 + t;
  float2 acc[8];
  #pragma unroll
  for (int r = 0; r < 8; ++r) acc[r] = make_float2(0.f, 0.f);
  for (int c = 0; c < 64; ++c) {
    float2 v = src[(size_t)c * 16384];
    #pragma unroll
    for (int r = 0; r < 8; ++r) {
      float u = sU[c * 16 + r0 + r];
      acc[r].x = fmaf(v.x, u, acc[r].x);
      acc[r].y = fmaf(v.y, u, acc[r].y);
    }
  }
  float2* dst = P + (((size_t)b * 16 + r0) * 64 + z) * 256 + t;
  #pragma unroll
  for (int r = 0; r < 8; ++r) dst[(size_t)r * 16384] = acc[r];
}

// ---------------- fused z-chain: P -> (fwd z) -> scale -> (inv z) -> Q -----
// slot k<16: freq k; slot 16+k: freq 48+k. All twiddles literal.
// Y splits the inverse-z output range into quarters.
template <int Y>
__device__ __forceinline__ void inv_z_q(const float* __restrict__ gr,
                                        const float* __restrict__ gi,
                                        float2* __restrict__ dst) {
  if (Y == 0) {   // z = 0
    float sr = 0.f, si = 0.f;
    #pragma unroll
    for (int k = 0; k < 32; ++k) { sr += gr[k]; si += gi[k]; }
    dst[0] = make_float2(sr, si);
  }
  if (Y == 2) {   // z = 32
    float sr = 0.f, si = 0.f;
    #pragma unroll
    for (int k = 0; k < 32; ++k) {
      if (k & 1) { sr -= gr[k]; si -= gi[k]; }
      else       { sr += gr[k]; si += gi[k]; }
    }
    dst[32 * 256] = make_float2(sr, si);
  }
  constexpr int z0 = (Y == 0) ? 1 : (Y == 1) ? 9 : (Y == 2) ? 17 : 25;
  constexpr int z1 = (Y == 0) ? 8 : (Y == 1) ? 16 : (Y == 2) ? 24 : 31;
  #pragma unroll
  for (int z = z0; z <= z1; ++z) {
    float Ar = 0.f, Ai = 0.f, Br = 0.f, Bi = 0.f;
    #pragma unroll
    for (int k = 0; k < 32; ++k) {
      const int f = (k < 16) ? k : (k + 32);
      const float c = cos64f(z * f), s = sin64f(z * f);
      Ar = fmaf(gr[k], c, Ar); Ai = fmaf(gi[k], c, Ai);
      Br = fmaf(gr[k], s, Br); Bi = fmaf(gi[k], s, Bi);
    }
    dst[z * 256] = make_float2(Ar - Bi, Ai + Br);
    dst[(64 - z) * 256] = make_float2(Ar + Bi, Ai - Br);
  }
}

__global__ __launch_bounds__(256) void k_zmix(
    const float2* __restrict__ P, float2* __restrict__ Q,
    const float* __restrict__ U_z, const float* __restrict__ U_h,
    const float* __restrict__ U_w, const float* __restrict__ U_z2,
    const float* __restrict__ U_h2, const float* __restrict__ S4) {
  int br = blockIdx.x, r = br & 15, t = threadIdx.x;
  int hf = t & 15, wf = ((t >> 4) & 3) + 4 * (t >> 6);
  const float2* src = P + (size_t)br * 16384 + t;
  // forward z (paired, literal): acc[k] = slot-k coefficient
  float2 acc[32];
  {
    float2 v0 = src[0], v32 = src[32 * 256];
    #pragma unroll
    for (int k = 0; k < 16; ++k) {
      float sgn = (k & 1) ? -1.f : 1.f;   // (-1)^k == (-1)^(48+k)
      float2 e = make_float2(v0.x + sgn * v32.x, v0.y + sgn * v32.y);
      acc[k] = e;
      acc[k + 16] = e;
    }
  }
  #pragma unroll
  for (int z = 1; z < 32; ++z) {
    float2 a = src[z * 256], b = src[(64 - z) * 256];
    float Sr = a.x + b.x, Si = a.y + b.y;
    float Dr = a.x - b.x, Di = a.y - b.y;
    #pragma unroll
    for (int k = 0; k < 16; ++k) {
      {
        const float c = cos64f(z * k), s = sin64f(z * k);
        acc[k].x = fmaf(Sr, c, fmaf(Di, s, acc[k].x));
        acc[k].y = fmaf(Si, c, fmaf(-Dr, s, acc[k].y));
      }
      {
        const float c = cos64f(z * (k + 48)), s = sin64f(z * (k + 48));
        acc[k + 16].x = fmaf(Sr, c, fmaf(Di, s, acc[k + 16].x));
        acc[k + 16].y = fmaf(Si, c, fmaf(-Dr, s, acc[k + 16].y));
      }
    }
  }
  // mode scale
  const float invN = 1.0f / 262144.0f;
  float S1r = S4[0] * invN, S1i = S4[1] * invN;
  float S2r = S4[2] * invN, S2i = S4[3] * invN;
  float cw = U_w[hf * 16 + r];
  float ch1 = U_h[wf * 16 + r] * cw, ch2 = U_h2[wf * 16 + r] * cw;
  float gr[32], gi[32];
  #pragma unroll
  for (int k = 0; k < 16; ++k) {
    float2 v = acc[k];
    float g = U_z[k * 16 + r] * ch1;
    float Fr = S1r * g, Fi = S1i * g;
    gr[k] = v.x * Fr - v.y * Fi;
    gi[k] = v.x * Fi + v.y * Fr;
  }
  #pragma unroll
  for (int k = 0; k < 16; ++k) {
    float2 v = acc[k + 16];
    float g = U_z2[k * 16 + r] * ch2;
    float Fr = S2r * g, Fi = S2i * g;
    gr[k + 16] = v.x * Fr - v.y * Fi;
    gi[k + 16] = v.x * Fi + v.y * Fr;
  }
  float2* dst = Q + (size_t)br * 16384 + t;
  switch (blockIdx.y) {
    case 0: inv_z_q<0>(gr, gi, dst); break;
    case 1: inv_z_q<1>(gr, gi, dst); break;
    case 2: inv_z_q<2>(gr, gi, dst); break;
    default: inv_z_q<3>(gr, gi, dst); break;
  }
}

// ---------------- fused o-expand + inverse H + real inverse W --------------
// grid (b*64+z, og=4); block 256. Wave expands its own o into private LDS
// tile (same-wave producer/consumer: no barrier), then literal iH + c2r-W.
// U_out rows are wave-uniform -> registers; LDS = 40960 B -> 4 blocks/CU.
__global__ __launch_bounds__(256) void k_inv_hw_ex(
    const float2* __restrict__ Q, float* __restrict__ out,
    const float* __restrict__ U_out) {
  __shared__ float2 sQ[16][256];     // 32768 B
  __shared__ float2 GLo[4][256];     //  8192 B
  int t = threadIdx.x;
  int b = blockIdx.x >> 6, z = blockIdx.x & 63, og = blockIdx.y;
  #pragma unroll
  for (int r = 0; r < 16; ++r)
    sQ[r][t] = Q[((size_t)(b * 16 + r) * 64 + z) * 256 + t];
  __syncthreads();
  int wave = t >> 6, lane = t & 63;
  // E2[wf] = 2 e^{+2pi i w wf/64}, w = lane (hoisted across o-loop)
  float2 E2[16];
  {
    float s, c;
    sincosf((TWOPI / 64.f) * (float)lane, &s, &c);
    float2 E = make_float2(c, s);
    float2 St = E;
    #pragma unroll
    for (int wfi = 1; wfi < 16; ++wfi) {
      E2[wfi] = make_float2(E.x + E.x, E.y + E.y);
      float ex = E.x * St.x - E.y * St.y;
      E.y = fmaf(E.x, St.y, E.y * St.x);
      E.x = ex;
    }
  }
  for (int oi = 0; oi < 4; ++oi) {
    int o = og * 16 + wave * 4 + oi;   // wave-uniform
    float uo[16];
    #pragma unroll
    for (int r = 0; r < 16; ++r) uo[r] = U_out[o * 16 + r];
    // expand rank-16 -> channel o into this wave's LDS tile (t-layout)
    #pragma unroll
    for (int q = 0; q < 4; ++q) {
      int tt = lane + 64 * q;
      float re = 0.f, im = 0.f;
      #pragma unroll
      for (int r = 0; r < 16; ++r) {
        float2 v = sQ[r][tt];
        re = fmaf(v.x, uo[r], re);
        im = fmaf(v.y, uo[r], im);
      }
      GLo[wave][tt] = make_float2(re, im);
    }
    // w-combine: q[hf] = GLo[t(hf,0)] + sum_{wf>=1} GLo[t(hf,wf)]*E2[wf]
    float qre[16], qim[16];
    #pragma unroll
    for (int hfi = 0; hfi < 16; ++hfi) {
      float2 g0 = GLo[wave][hfi];     // t(hf,0) = hf
      float ar = g0.x, ai = g0.y;
      #pragma unroll
      for (int wfi = 1; wfi < 16; ++wfi) {
        float2 gv = GLo[wave][(wfi >> 2) * 64 + (wfi & 3) * 16 + hfi];
        ar = fmaf(gv.x, E2[wfi].x, fmaf(-gv.y, E2[wfi].y, ar));
        ai = fmaf(gv.x, E2[wfi].y, fmaf(gv.y, E2[wfi].x, ai));
      }
      qre[hfi] = ar; qim[hfi] = ai;
    }
    // h-inverse (literal twiddles, h/64-h pairing), coalesced nt stores
    float* op = out + (((size_t)(b * 64 + o) * 64 + z)) * 4096 + lane;
    {
      float Pv = qre[0];
      #pragma unroll
      for (int hfi = 1; hfi < 16; ++hfi) Pv += qre[hfi];
      __builtin_nontemporal_store(Pv, op);
    }
    {
      float Pv = qre[0];
      #pragma unroll
      for (int hfi = 1; hfi < 16; ++hfi)
        Pv += (hfi & 1) ? -qre[hfi] : qre[hfi];
      __builtin_nontemporal_store(Pv, op + 32 * 64);
    }
    #pragma unroll
    for (int h = 1; h < 32; ++h) {
      float Pv = qre[0], Qv = 0.f;
      #pragma unroll
      for (int hfi = 1; hfi < 16; ++hfi) {
        Pv = fmaf(qre[hfi], cos64f(h * hfi), Pv);
        Qv = fmaf(qim[hfi], sin64f(h * hfi), Qv);
      }
      __builtin_nontemporal_store(Pv - Qv, op + h * 64);
      __builtin_nontemporal_store(Pv + Qv, op + (64 - h) * 64);
    }
  }
}

extern "C" void kernel_launch(void* const* d_in, const int* in_sizes, int n_in,
                              void* d_out, int out_size, void* d_ws,
                              size_t ws_size, hipStream_t stream) {
  const float* x    = (const float*)d_in[0];
  const float* Uin  = (const float*)d_in[1];
  const float* Uout = (const float*)d_in[2];
  const float* Uz   = (const float*)d_in[3];
  const float* Uh   = (const float*)d_in[4];
  const float* Uw   = (const float*)d_in[5];
  const float* Uz2  = (const float*)d_in[6];
  const float* Uh2  = (const float*)d_in[7];
  const float* cr   = (const float*)d_in[8];
  const float* ci   = (const float*)d_in[9];
  const float* c2r  = (const float*)d_in[10];
  const float* c2i  = (const float*)d_in[11];
  float* outp = (float*)d_out;

  char* ws = (char*)d_ws;
  float* S       = (float*)ws;            // 4 floats
  float* partial = (float*)(ws + 256);    // 256 floats
  float2* A2 = (float2*)(ws + 4096);                 // 33,554,432 B
  float2* P  = (float2*)(ws + 33558528);             //  8,388,608 B
  float2* Q  = (float2*)(ws + 41947136);             // 16,777,216 B

  k_fwd_wh_core<<<4352, 256, 0, stream>>>(x, A2, cr, ci, c2r, c2i, partial);
  k_proj<<<dim3(256, 2), 256, 0, stream>>>(A2, P, Uin, partial, S);
  k_zmix<<<dim3(64, 4), 256, 0, stream>>>(P, Q, Uz, Uh, Uw, Uz2, Uh2, S);
  k_inv_hw_ex<<<dim3(256, 4), 256, 0, stream>>>(Q, outp, Uout);
}

// Round 15
// 164.306 us; speedup vs baseline: 1.6478x; 1.6478x over previous
//
#include <hip/hip_runtime.h>

// Problem constants: B=4, C=64, Z=H=W=64, modes 16, rank 16.
#define TWOPI 6.28318530717958647692f

// cos/sin(2*pi*k/64) as constexpr (compile-time literals after full unroll)
constexpr float COSQ[17] = {
  1.0f, 0.995184727f, 0.980785280f, 0.956940336f, 0.923879533f,
  0.881921264f, 0.831469612f, 0.773010453f, 0.707106781f,
  0.634393284f, 0.555570233f, 0.471396737f, 0.382683432f,
  0.290284677f, 0.195090322f, 0.098017140f, 0.0f
};
__host__ __device__ constexpr float cos64f(int k) {
  k &= 63;
  return (k <= 16) ? COSQ[k] : (k < 32) ? -COSQ[32 - k]
       : (k <= 48) ? -COSQ[k - 32] : COSQ[64 - k];
}
__host__ __device__ constexpr float sin64f(int k) { return cos64f(k + 48); }

// t-layout of the 256 (hf,wf) pairs:  t = j*64 + wq*16 + hf, wf = wq+4j.
// decode: hf = t&15, wf = ((t>>4)&3) + 4*(t>>6); encode: t(hf,wf) =
// (wf>>2)*64 + (wf&3)*16 + hf.

// ---------------- fused: core partial sums + forward H+W DFT ---------------
// blocks 0..255: core-tensor partial reduction (overlaps its 67 MB read with
// the DFT blocks). blocks 256..4351: one (b,c,z) plane per wave.
__global__ __launch_bounds__(256) void k_fwd_wh_core(
    const float* __restrict__ x, float2* __restrict__ A2,
    const float* __restrict__ a0, const float* __restrict__ a1,
    const float* __restrict__ a2, const float* __restrict__ a3,
    float* __restrict__ partial) {
  __shared__ float2 T[4][64][17];   // [w][hf], pad 17 (fwd branch)
  __shared__ float red[256];        // core branch
  if (blockIdx.x < 256) {
    int bx = blockIdx.x & 63, by = blockIdx.x >> 6;
    const float* p = by == 0 ? a0 : by == 1 ? a1 : by == 2 ? a2 : a3;
    const float4* p4 = (const float4*)p;
    float s = 0.f;
    int base = bx * 4096 + threadIdx.x;
    #pragma unroll
    for (int i = 0; i < 16; ++i) {
      float4 v = p4[base + i * 256];
      s += (v.x + v.y) + (v.z + v.w);
    }
    red[threadIdx.x] = s;
    __syncthreads();
    for (int off = 128; off; off >>= 1) {
      if (threadIdx.x < off) red[threadIdx.x] += red[threadIdx.x + off];
      __syncthreads();
    }
    if (threadIdx.x == 0) partial[by * 64 + bx] = red[0];
    return;
  }
  int wave = threadIdx.x >> 6, lane = threadIdx.x & 63;
  int plane = (blockIdx.x - 256) * 4 + wave;     // (b*64+c)*64+z
  const float* xp = x + (size_t)plane * 4096 + lane;   // lane = w
  // stage 1: col[hf] = sum_h x[h][w] e^{-2pi i h hf/64}, literal twiddles
  float cre[16], cim[16];
  {
    float x0 = xp[0], x32 = xp[32 * 64];
    #pragma unroll
    for (int hf = 0; hf < 16; ++hf) {
      cre[hf] = x0 + ((hf & 1) ? -x32 : x32);
      cim[hf] = 0.f;
    }
  }
  #pragma unroll
  for (int h = 1; h < 32; ++h) {
    float va = xp[h * 64], vb = xp[(64 - h) * 64];
    float u = va + vb, d = va - vb;
    #pragma unroll
    for (int hf = 0; hf < 16; ++hf) {
      cre[hf] = fmaf(u, cos64f(h * hf), cre[hf]);
      cim[hf] = fmaf(d, -sin64f(h * hf), cim[hf]);
    }
  }
  #pragma unroll
  for (int hf = 0; hf < 16; ++hf)
    T[wave][lane][hf] = make_float2(cre[hf], cim[hf]);
  __syncthreads();
  // stage 2 (paired): A[hf][wf] = sum_w T[w][hf] e^{-2pi i w wf/64}
  int hf = lane & 15, wq = lane >> 4;
  float2 rot[4], CS[4], acc[4];
  float2 T0 = T[wave][0][hf], T32 = T[wave][32][hf];
  #pragma unroll
  for (int j = 0; j < 4; ++j) {
    int wf = wq + 4 * j;
    float s, c;
    sincosf((TWOPI / 64.f) * (float)wf, &s, &c);
    rot[j] = make_float2(c, s);
    CS[j] = make_float2(c, s);        // value at w=1
    float sgn = (wf & 1) ? -1.f : 1.f;
    acc[j] = make_float2(T0.x + sgn * T32.x, T0.y + sgn * T32.y);
  }
  #pragma unroll 4
  for (int w = 1; w < 32; ++w) {
    float2 a = T[wave][w][hf], b2 = T[wave][64 - w][hf];
    float Sr = a.x + b2.x, Si = a.y + b2.y;
    float Dr = a.x - b2.x, Di = a.y - b2.y;
    #pragma unroll
    for (int j = 0; j < 4; ++j) {
      float C = CS[j].x, Sn = CS[j].y;
      acc[j].x = fmaf(Sr, C, fmaf(Di, Sn, acc[j].x));
      acc[j].y = fmaf(Si, C, fmaf(-Dr, Sn, acc[j].y));
      float nC = C * rot[j].x - Sn * rot[j].y;
      CS[j].y = fmaf(C, rot[j].y, Sn * rot[j].x);
      CS[j].x = nC;
    }
  }
  float2* dst = A2 + (size_t)plane * 256 + lane;   // t = j*64+lane
  #pragma unroll
  for (int j = 0; j < 4; ++j) dst[j * 64] = acc[j];
}

// ---------------- projection c -> r (+ fused core-final sum) ---------------
// grid (256 bz, 2 rg): each block computes 8 of the 16 ranks.
__global__ __launch_bounds__(256) void k_proj(const float2* __restrict__ A2,
                                              float2* __restrict__ P,
                                              const float* __restrict__ U_in,
                                              const float* __restrict__ partial,
                                              float* __restrict__ S) {
  if (blockIdx.x == 0 && blockIdx.y == 0 && threadIdx.x < 4) {
    float s = 0.f;
    for (int j = 0; j < 64; ++j) s += partial[threadIdx.x * 64 + j];
    S[threadIdx.x] = s;
  }
  __shared__ float sU[1024];
  int t = threadIdx.x;
  #pragma unroll
  for (int i = 0; i < 4; ++i) sU[t + 256 * i] = U_in[t + 256 * i];
  __syncthreads();
  int b = blockIdx.x >> 6, z = blockIdx.x & 63, r0 = blockIdx.y * 8;
  const float2* src = A2 + (((size_t)b * 64) * 64 + z) * 256 + t;
  float2 acc[8];
  #pragma unroll
  for (int r = 0; r < 8; ++r) acc[r] = make_float2(0.f, 0.f);
  for (int c = 0; c < 64; ++c) {
    float2 v = src[(size_t)c * 16384];
    #pragma unroll
    for (int r = 0; r < 8; ++r) {
      float u = sU[c * 16 + r0 + r];
      acc[r].x = fmaf(v.x, u, acc[r].x);
      acc[r].y = fmaf(v.y, u, acc[r].y);
    }
  }
  float2* dst = P + (((size_t)b * 16 + r0) * 64 + z) * 256 + t;
  #pragma unroll
  for (int r = 0; r < 8; ++r) dst[(size_t)r * 16384] = acc[r];
}

// ---------------- fused z-chain: P -> (fwd z) -> scale -> (inv z) -> Q -----
// slot k<16: freq k; slot 16+k: freq 48+k. All twiddles literal.
// Y splits the inverse-z output range into quarters.
template <int Y>
__device__ __forceinline__ void inv_z_q(const float* __restrict__ gr,
                                        const float* __restrict__ gi,
                                        float2* __restrict__ dst) {
  if (Y == 0) {   // z = 0
    float sr = 0.f, si = 0.f;
    #pragma unroll
    for (int k = 0; k < 32; ++k) { sr += gr[k]; si += gi[k]; }
    dst[0] = make_float2(sr, si);
  }
  if (Y == 2) {   // z = 32
    float sr = 0.f, si = 0.f;
    #pragma unroll
    for (int k = 0; k < 32; ++k) {
      if (k & 1) { sr -= gr[k]; si -= gi[k]; }
      else       { sr += gr[k]; si += gi[k]; }
    }
    dst[32 * 256] = make_float2(sr, si);
  }
  constexpr int z0 = (Y == 0) ? 1 : (Y == 1) ? 9 : (Y == 2) ? 17 : 25;
  constexpr int z1 = (Y == 0) ? 8 : (Y == 1) ? 16 : (Y == 2) ? 24 : 31;
  #pragma unroll
  for (int z = z0; z <= z1; ++z) {
    float Ar = 0.f, Ai = 0.f, Br = 0.f, Bi = 0.f;
    #pragma unroll
    for (int k = 0; k < 32; ++k) {
      const int f = (k < 16) ? k : (k + 32);
      const float c = cos64f(z * f), s = sin64f(z * f);
      Ar = fmaf(gr[k], c, Ar); Ai = fmaf(gi[k], c, Ai);
      Br = fmaf(gr[k], s, Br); Bi = fmaf(gi[k], s, Bi);
    }
    dst[z * 256] = make_float2(Ar - Bi, Ai + Br);
    dst[(64 - z) * 256] = make_float2(Ar + Bi, Ai - Br);
  }
}

__global__ __launch_bounds__(256) void k_zmix(
    const float2* __restrict__ P, float2* __restrict__ Q,
    const float* __restrict__ U_z, const float* __restrict__ U_h,
    const float* __restrict__ U_w, const float* __restrict__ U_z2,
    const float* __restrict__ U_h2, const float* __restrict__ S4) {
  int br = blockIdx.x, r = br & 15, t = threadIdx.x;
  int hf = t & 15, wf = ((t >> 4) & 3) + 4 * (t >> 6);
  const float2* src = P + (size_t)br * 16384 + t;
  // forward z (paired, literal): acc[k] = slot-k coefficient
  float2 acc[32];
  {
    float2 v0 = src[0], v32 = src[32 * 256];
    #pragma unroll
    for (int k = 0; k < 16; ++k) {
      float sgn = (k & 1) ? -1.f : 1.f;   // (-1)^k == (-1)^(48+k)
      float2 e = make_float2(v0.x + sgn * v32.x, v0.y + sgn * v32.y);
      acc[k] = e;
      acc[k + 16] = e;
    }
  }
  #pragma unroll
  for (int z = 1; z < 32; ++z) {
    float2 a = src[z * 256], b = src[(64 - z) * 256];
    float Sr = a.x + b.x, Si = a.y + b.y;
    float Dr = a.x - b.x, Di = a.y - b.y;
    #pragma unroll
    for (int k = 0; k < 16; ++k) {
      {
        const float c = cos64f(z * k), s = sin64f(z * k);
        acc[k].x = fmaf(Sr, c, fmaf(Di, s, acc[k].x));
        acc[k].y = fmaf(Si, c, fmaf(-Dr, s, acc[k].y));
      }
      {
        const float c = cos64f(z * (k + 48)), s = sin64f(z * (k + 48));
        acc[k + 16].x = fmaf(Sr, c, fmaf(Di, s, acc[k + 16].x));
        acc[k + 16].y = fmaf(Si, c, fmaf(-Dr, s, acc[k + 16].y));
      }
    }
  }
  // mode scale
  const float invN = 1.0f / 262144.0f;
  float S1r = S4[0] * invN, S1i = S4[1] * invN;
  float S2r = S4[2] * invN, S2i = S4[3] * invN;
  float cw = U_w[hf * 16 + r];
  float ch1 = U_h[wf * 16 + r] * cw, ch2 = U_h2[wf * 16 + r] * cw;
  float gr[32], gi[32];
  #pragma unroll
  for (int k = 0; k < 16; ++k) {
    float2 v = acc[k];
    float g = U_z[k * 16 + r] * ch1;
    float Fr = S1r * g, Fi = S1i * g;
    gr[k] = v.x * Fr - v.y * Fi;
    gi[k] = v.x * Fi + v.y * Fr;
  }
  #pragma unroll
  for (int k = 0; k < 16; ++k) {
    float2 v = acc[k + 16];
    float g = U_z2[k * 16 + r] * ch2;
    float Fr = S2r * g, Fi = S2i * g;
    gr[k + 16] = v.x * Fr - v.y * Fi;
    gi[k + 16] = v.x * Fi + v.y * Fr;
  }
  float2* dst = Q + (size_t)br * 16384 + t;
  switch (blockIdx.y) {
    case 0: inv_z_q<0>(gr, gi, dst); break;
    case 1: inv_z_q<1>(gr, gi, dst); break;
    case 2: inv_z_q<2>(gr, gi, dst); break;
    default: inv_z_q<3>(gr, gi, dst); break;
  }
}

// ---------------- fused o-expand + inverse H + real inverse W --------------
// grid (b*64+z, og=4); block 256. Wave expands its own o into private LDS
// tile (same-wave producer/consumer: no barrier), then literal iH + c2r-W.
// Output stores are nontemporal: out is write-once; keep L2/L3 for x and Q.
__global__ __launch_bounds__(256) void k_inv_hw_ex(
    const float2* __restrict__ Q, float* __restrict__ out,
    const float* __restrict__ U_out) {
  __shared__ float2 sQ[16][256];
  __shared__ float2 GLo[4][256];
  __shared__ float sU[256];          // only this block's 16 o-rows
  int t = threadIdx.x;
  int b = blockIdx.x >> 6, z = blockIdx.x & 63, og = blockIdx.y;
  sU[t] = U_out[og * 256 + t];       // sU[(o-og*16)*16 + r]
  #pragma unroll
  for (int r = 0; r < 16; ++r)
    sQ[r][t] = Q[((size_t)(b * 16 + r) * 64 + z) * 256 + t];
  __syncthreads();
  int wave = t >> 6, lane = t & 63;
  // E2[wf] = 2 e^{+2pi i w wf/64}, w = lane (hoisted across o-loop)
  float2 E2[16];
  {
    float s, c;
    sincosf((TWOPI / 64.f) * (float)lane, &s, &c);
    float2 E = make_float2(c, s);
    float2 St = E;
    #pragma unroll
    for (int wfi = 1; wfi < 16; ++wfi) {
      E2[wfi] = make_float2(E.x + E.x, E.y + E.y);
      float ex = E.x * St.x - E.y * St.y;
      E.y = fmaf(E.x, St.y, E.y * St.x);
      E.x = ex;
    }
  }
  for (int oi = 0; oi < 4; ++oi) {
    int ol = wave * 4 + oi;          // local o index 0..15
    int o = og * 16 + ol;
    // expand rank-16 -> channel o into this wave's LDS tile (t-layout)
    #pragma unroll
    for (int q = 0; q < 4; ++q) {
      int tt = lane + 64 * q;
      float re = 0.f, im = 0.f;
      #pragma unroll
      for (int r = 0; r < 16; ++r) {
        float u = sU[ol * 16 + r];
        float2 v = sQ[r][tt];
        re = fmaf(v.x, u, re);
        im = fmaf(v.y, u, im);
      }
      GLo[wave][tt] = make_float2(re, im);
    }
    // w-combine: q[hf] = GLo[t(hf,0)] + sum_{wf>=1} GLo[t(hf,wf)]*E2[wf]
    float qre[16], qim[16];
    #pragma unroll
    for (int hfi = 0; hfi < 16; ++hfi) {
      float2 g0 = GLo[wave][hfi];     // t(hf,0) = hf
      float ar = g0.x, ai = g0.y;
      #pragma unroll
      for (int wfi = 1; wfi < 16; ++wfi) {
        float2 gv = GLo[wave][(wfi >> 2) * 64 + (wfi & 3) * 16 + hfi];
        ar = fmaf(gv.x, E2[wfi].x, fmaf(-gv.y, E2[wfi].y, ar));
        ai = fmaf(gv.x, E2[wfi].y, fmaf(gv.y, E2[wfi].x, ai));
      }
      qre[hfi] = ar; qim[hfi] = ai;
    }
    // h-inverse (literal twiddles, h/64-h pairing), coalesced nt stores
    float* op = out + (((size_t)(b * 64 + o) * 64 + z)) * 4096 + lane;
    {
      float Pv = qre[0];
      #pragma unroll
      for (int hfi = 1; hfi < 16; ++hfi) Pv += qre[hfi];
      __builtin_nontemporal_store(Pv, op);
    }
    {
      float Pv = qre[0];
      #pragma unroll
      for (int hfi = 1; hfi < 16; ++hfi)
        Pv += (hfi & 1) ? -qre[hfi] : qre[hfi];
      __builtin_nontemporal_store(Pv, op + 32 * 64);
    }
    #pragma unroll
    for (int h = 1; h < 32; ++h) {
      float Pv = qre[0], Qv = 0.f;
      #pragma unroll
      for (int hfi = 1; hfi < 16; ++hfi) {
        Pv = fmaf(qre[hfi], cos64f(h * hfi), Pv);
        Qv = fmaf(qim[hfi], sin64f(h * hfi), Qv);
      }
      __builtin_nontemporal_store(Pv - Qv, op + h * 64);
      __builtin_nontemporal_store(Pv + Qv, op + (64 - h) * 64);
    }
  }
}

extern "C" void kernel_launch(void* const* d_in, const int* in_sizes, int n_in,
                              void* d_out, int out_size, void* d_ws,
                              size_t ws_size, hipStream_t stream) {
  const float* x    = (const float*)d_in[0];
  const float* Uin  = (const float*)d_in[1];
  const float* Uout = (const float*)d_in[2];
  const float* Uz   = (const float*)d_in[3];
  const float* Uh   = (const float*)d_in[4];
  const float* Uw   = (const float*)d_in[5];
  const float* Uz2  = (const float*)d_in[6];
  const float* Uh2  = (const float*)d_in[7];
  const float* cr   = (const float*)d_in[8];
  const float* ci   = (const float*)d_in[9];
  const float* c2r  = (const float*)d_in[10];
  const float* c2i  = (const float*)d_in[11];
  float* outp = (float*)d_out;

  char* ws = (char*)d_ws;
  float* S       = (float*)ws;            // 4 floats
  float* partial = (float*)(ws + 256);    // 256 floats
  float2* A2 = (float2*)(ws + 4096);                 // 33,554,432 B
  float2* P  = (float2*)(ws + 33558528);             //  8,388,608 B
  float2* Q  = (float2*)(ws + 41947136);             // 16,777,216 B

  k_fwd_wh_core<<<4352, 256, 0, stream>>>(x, A2, cr, ci, c2r, c2i, partial);
  k_proj<<<dim3(256, 2), 256, 0, stream>>>(A2, P, Uin, partial, S);
  k_zmix<<<dim3(64, 4), 256, 0, stream>>>(P, Q, Uz, Uh, Uw, Uz2, Uh2, S);
  k_inv_hw_ex<<<dim3(256, 4), 256, 0, stream>>>(Q, outp, Uout);
}